// Round 12
// baseline (30146.042 us; speedup 1.0000x reference)
//
#include <hip/hip_runtime.h>
#include <hip/hip_bf16.h>
#include <math.h>

// Fused LM-head cross-entropy: loss = mean_valid( logsumexp(x@W^T) - logit[y] )
// N=4096 tokens, H=4096 hidden, V=128000 vocab.
//
// Round 12: MX-fp8 (identity scales) at 256x256 tile, SINGLE-buffered 64KB
// LDS -> 2 blocks/CU. Simple m97 2-barrier loop; cross-block desync hides
// the stage drain under the other block's MFMA. Combines R10's reuse
// (FETCH 2.6GB) with R11's occupancy (2+ blocks/CU).

#define N_ROWS 4096
#define H_DIM  4096
#define V_DIM  128000
#define BM 256
#define BN 256
#define NT_N (N_ROWS / BM)      // 16
#define NT_V (V_DIM / BN)       // 500
#define NKT  (H_DIM / 128)      // 32 K-tiles (128 fp8 elems each)
#define IGNORE_INDEX (-100)

typedef __attribute__((ext_vector_type(4))) int   i32x4;
typedef __attribute__((ext_vector_type(8))) int   i32x8;
typedef __attribute__((ext_vector_type(4))) float f32x4;
typedef __attribute__((ext_vector_type(16))) float f32x16;
typedef const __attribute__((address_space(1))) unsigned int* gas1_u32;
typedef __attribute__((address_space(3))) unsigned int* las3_u32;

// ---------------- exact f32 -> e4m3fn (OCP), RNE, saturating ----------------
__device__ __forceinline__ unsigned f2e4m3(float f) {
    unsigned u = __float_as_uint(f);
    unsigned s = (u >> 24) & 0x80u;
    float af = __uint_as_float(u & 0x7FFFFFFFu);
    unsigned code;
    if (af >= 0.015625f) {                       // normal range [2^-6, 448]
        if (af > 448.f) af = 448.f;
        unsigned v = __float_as_uint(af);
        v += 0x7FFFFu + ((v >> 20) & 1u);        // RNE to 3 mantissa bits
        unsigned m3 = (v >> 20) & 7u;
        int E = (int)(v >> 23) - 127;
        if (E > 8) { E = 8; m3 = 6u; }           // clamp to 448
        code = (unsigned)((E + 7) << 3) | m3;
    } else {                                      // subnormal: m * 2^-9
        code = (unsigned)rintf(af * 512.0f);     // 0..8 (8 -> 2^-6 seamlessly)
    }
    return s | code;
}

__global__ void cvt_f32_fp8_kernel(const float* __restrict__ in,
                                   unsigned char* __restrict__ out, size_t n, float scale)
{
    size_t i = ((size_t)blockIdx.x * blockDim.x + threadIdx.x) * 8;
    size_t stride = (size_t)gridDim.x * blockDim.x * 8;
    for (; i < n; i += stride) {
        f32x4 a = *(const f32x4*)(in + i);
        f32x4 b = *(const f32x4*)(in + i + 4);
        unsigned long long o;
        o  = (unsigned long long)f2e4m3(a.x * scale);
        o |= (unsigned long long)f2e4m3(a.y * scale) << 8;
        o |= (unsigned long long)f2e4m3(a.z * scale) << 16;
        o |= (unsigned long long)f2e4m3(a.w * scale) << 24;
        o |= (unsigned long long)f2e4m3(b.x * scale) << 32;
        o |= (unsigned long long)f2e4m3(b.y * scale) << 40;
        o |= (unsigned long long)f2e4m3(b.z * scale) << 48;
        o |= (unsigned long long)f2e4m3(b.w * scale) << 56;
        *(unsigned long long*)(out + i) = o;
    }
}

#define SCL1 ((int)0x7F7F7F7F)   // E8M0 127 = 2^0 in every byte (identity)

// 32B fragment read: low 16B at off, high 16B at off^16 (k-base is 32-aligned
// so the XOR swizzle preserves k-ascending byte order across the pair).
__device__ __forceinline__ i32x8 rd32(const char* base, int off) {
    i32x8 r;
    *(i32x4*)&r       = *(const i32x4*)(base + off);
    *((i32x4*)&r + 1) = *(const i32x4*)(base + (off ^ 16));
    return r;
}

// ------------------- 256^2 single-buffered MX-fp8 GEMM -------------------
__global__ __launch_bounds__(512, 4)
void lmce_gemm256_kernel(const unsigned char* __restrict__ Xq, const unsigned char* __restrict__ Wq,
                         float* __restrict__ pm, float* __restrict__ pl)
{
    __shared__ __align__(16) char lsA[256 * 128];   // 32KB: [256 rows][128 k-bytes]
    __shared__ __align__(16) char lsB[256 * 128];   // 32KB
    __shared__ float red_m[4][BM];
    __shared__ float red_l[4][BM];

    // bijective XCD swizzle: nwg = 8000, divisible by 8; consecutive wgs in a
    // chunk share the vtile (W panel L2-resident per XCD).
    const int nwg = NT_N * NT_V;
    int orig = blockIdx.x;
    int wg = (orig & 7) * (nwg >> 3) + (orig >> 3);
    int vtile = wg / NT_N;
    int ntile = wg - vtile * NT_N;

    int tid  = threadIdx.x;
    int lane = tid & 63;
    int w    = tid >> 6;          // 0..7
    int wr = w >> 2;              // 0..1 : 128-row half of A
    int wc = w & 3;               // 0..3 : 64-col strip of B
    int l31  = lane & 31;
    int kb   = (lane >> 5) * 32;  // k-byte base within a 64-elem step

    // staging: chunk j covers LDS bytes [j*8192 + tid*16); row = j*64+(tid>>3),
    // 16B at source col pre-swizzled with the same XOR the reads use.
    int srow = tid >> 3;                          // 0..63 within chunk
    int scolb = ((tid & 7) * 16) ^ ((srow & 7) << 4);
    const char* gA[4];
    const char* gB[4];
    #pragma unroll
    for (int j = 0; j < 4; ++j) {
        gA[j] = (const char*)Xq + (size_t)(ntile * BM + j * 64 + srow) * 4096 + scolb;
        gB[j] = (const char*)Wq + (size_t)(vtile * BN + j * 64 + srow) * 4096 + scolb;
    }

    // swizzled ds_read offsets (flat [256][128] tiles); row&7 == l31&7
    int offA[4][2], offB[2][2];
    #pragma unroll
    for (int mi = 0; mi < 4; ++mi)
        #pragma unroll
        for (int ks = 0; ks < 2; ++ks) {
            int row = wr * 128 + mi * 32 + l31;
            offA[mi][ks] = row * 128 + ((kb + ks * 64) ^ ((l31 & 7) << 4));
        }
    #pragma unroll
    for (int ni = 0; ni < 2; ++ni)
        #pragma unroll
        for (int ks = 0; ks < 2; ++ks) {
            int row = wc * 64 + ni * 32 + l31;
            offB[ni][ks] = row * 128 + ((kb + ks * 64) ^ ((l31 & 7) << 4));
        }

    f32x16 acc[4][2];
    #pragma unroll
    for (int i = 0; i < 4; ++i)
        #pragma unroll
        for (int j = 0; j < 2; ++j)
            #pragma unroll
            for (int r = 0; r < 16; ++r)
                acc[i][j][r] = 0.f;

    for (int kt = 0; kt < NKT; ++kt) {
        size_t ko = (size_t)kt * 128;
        #pragma unroll
        for (int j = 0; j < 4; ++j) {
            __builtin_amdgcn_global_load_lds((gas1_u32)(gA[j] + ko),
                                             (las3_u32)(lsA + j * 8192 + tid * 16), 16, 0, 0);
            __builtin_amdgcn_global_load_lds((gas1_u32)(gB[j] + ko),
                                             (las3_u32)(lsB + j * 8192 + tid * 16), 16, 0, 0);
        }
        __syncthreads();   // drains vmcnt(0): tile ready

        i32x8 bF[2][2];
        #pragma unroll
        for (int ni = 0; ni < 2; ++ni)
            #pragma unroll
            for (int ks = 0; ks < 2; ++ks)
                bF[ni][ks] = rd32(lsB, offB[ni][ks]);
        i32x8 aF[4][2];
        #pragma unroll
        for (int mi = 0; mi < 4; ++mi)
            #pragma unroll
            for (int ks = 0; ks < 2; ++ks)
                aF[mi][ks] = rd32(lsA, offA[mi][ks]);

        #pragma unroll
        for (int ks = 0; ks < 2; ++ks)
            #pragma unroll
            for (int mi = 0; mi < 4; ++mi)
                #pragma unroll
                for (int ni = 0; ni < 2; ++ni)
                    acc[mi][ni] = __builtin_amdgcn_mfma_scale_f32_32x32x64_f8f6f4(
                        aF[mi][ks], bF[ni][ks], acc[mi][ni], 0, 0, 0, SCL1, 0, SCL1);

        __syncthreads();   // all waves done reading before next overwrite
    }

    // Epilogue: per-row max and sumexp over this block's 256 cols.
    // 32x32 C/D layout: col = lane&31, row = (r&3) + 8*(r>>2) + 4*(lane>>5).
    // Unscale logits by 2^-6 (W was stored x64) -- exact power of two.
    const float inv64 = 0.015625f;
    #pragma unroll
    for (int mi = 0; mi < 4; ++mi) {
        #pragma unroll
        for (int r = 0; r < 16; ++r) {
            float v0 = acc[mi][0][r] * inv64;
            float v1 = acc[mi][1][r] * inv64;
            float mx = fmaxf(v0, v1);
            #pragma unroll
            for (int s = 1; s < 32; s <<= 1)
                mx = fmaxf(mx, __shfl_xor(mx, s, 64));
            float se = __expf(v0 - mx) + __expf(v1 - mx);
            #pragma unroll
            for (int s = 1; s < 32; s <<= 1)
                se += __shfl_xor(se, s, 64);
            if (l31 == 0) {
                int rloc = wr * 128 + mi * 32 + (r & 3) + 8 * (r >> 2) + 4 * (lane >> 5);
                red_m[wc][rloc] = mx;
                red_l[wc][rloc] = se;
            }
        }
    }
    __syncthreads();
    if (tid < BM) {
        float mm = red_m[0][tid], ll = red_l[0][tid];
        #pragma unroll
        for (int p = 1; p < 4; ++p) {
            float m2 = red_m[p][tid], l2 = red_l[p][tid];
            float m3 = fmaxf(mm, m2);
            ll = ll * __expf(mm - m3) + l2 * __expf(m2 - m3);
            mm = m3;
        }
        size_t idx = (size_t)vtile * N_ROWS + (size_t)(ntile * BM + tid);
        pm[idx] = mm;
        pl[idx] = ll;
    }
}

// tgt[row] = dot(x[row], W[y[row]]) in fp32 (exact vs reference)
__global__ void lmce_tgt_kernel(const float* __restrict__ X, const float* __restrict__ W,
                                const int* __restrict__ y, float* __restrict__ tgt)
{
    int row = blockIdx.x;
    int tid = threadIdx.x;
    int yv = y[row];
    float s = 0.f;
    if (yv >= 0 && yv < V_DIM) {
        const float* xr = X + (size_t)row * H_DIM;
        const float* wrow = W + (size_t)yv * H_DIM;
        #pragma unroll
        for (int j = 0; j < 4; ++j) {
            int idx = (tid + j * 256) * 4;
            f32x4 a = *(const f32x4*)(xr + idx);
            f32x4 b = *(const f32x4*)(wrow + idx);
            s += a.x * b.x + a.y * b.y + a.z * b.z + a.w * b.w;
        }
    }
    #pragma unroll
    for (int sh = 1; sh < 64; sh <<= 1) s += __shfl_xor(s, sh, 64);
    __shared__ float sred[4];
    if ((tid & 63) == 0) sred[tid >> 6] = s;
    __syncthreads();
    if (tid == 0) tgt[row] = sred[0] + sred[1] + sred[2] + sred[3];
}

// merge NT_V per-vtile (m,l) partials per row -> lse[row]
__global__ void lmce_lse_kernel(const float* __restrict__ pm, const float* __restrict__ pl,
                                float* __restrict__ lse)
{
    int tid = threadIdx.x;
    int row = blockIdx.x * 64 + (tid & 63);
    int part = tid >> 6;               // 0..3, each scans NT_V/4 = 125 vtiles
    const int per = NT_V / 4;
    float m = -INFINITY, l = 0.f;
    for (int vt = part * per; vt < (part + 1) * per; ++vt) {
        size_t idx = (size_t)vt * N_ROWS + row;
        float m2 = pm[idx], l2 = pl[idx];
        float mm = fmaxf(m, m2);
        l = l * __expf(m - mm) + l2 * __expf(m2 - mm);
        m = mm;
    }
    __shared__ float sm[4][64], sl[4][64];
    sm[part][tid & 63] = m;
    sl[part][tid & 63] = l;
    __syncthreads();
    if (tid < 64) {
        float M = sm[0][tid], L = sl[0][tid];
        #pragma unroll
        for (int p = 1; p < 4; ++p) {
            float m2 = sm[p][tid], l2 = sl[p][tid];
            float mm = fmaxf(M, m2);
            L = L * __expf(M - mm) + l2 * __expf(m2 - mm);
            M = mm;
        }
        lse[blockIdx.x * 64 + tid] = M + logf(L);
    }
}

__global__ void lmce_final_kernel(const float* __restrict__ lse, const float* __restrict__ tgt,
                                  const int* __restrict__ y, float* __restrict__ out)
{
    int tid = threadIdx.x;
    float s = 0.f, c = 0.f;
    for (int i = tid; i < N_ROWS; i += 256) {
        if (y[i] != IGNORE_INDEX) {
            s += lse[i] - tgt[i];
            c += 1.f;
        }
    }
    #pragma unroll
    for (int sh = 1; sh < 64; sh <<= 1) {
        s += __shfl_xor(s, sh, 64);
        c += __shfl_xor(c, sh, 64);
    }
    __shared__ float ss[4], cc[4];
    if ((tid & 63) == 0) { ss[tid >> 6] = s; cc[tid >> 6] = c; }
    __syncthreads();
    if (tid == 0) {
        float S = ss[0] + ss[1] + ss[2] + ss[3];
        float C = cc[0] + cc[1] + cc[2] + cc[3];
        out[0] = S / fmaxf(C, 1.f);
    }
}

extern "C" void kernel_launch(void* const* d_in, const int* in_sizes, int n_in,
                              void* d_out, int out_size, void* d_ws, size_t ws_size,
                              hipStream_t stream)
{
    const float* X = (const float*)d_in[0];   // [4096, 4096] fp32
    const int*   y = (const int*)d_in[1];     // [4096] labels
    const float* W = (const float*)d_in[2];   // [128000, 4096] fp32
    float* out = (float*)d_out;

    char* ws = (char*)d_ws;
    const size_t OFF_PL  = 16384000;
    const size_t OFF_TGT = 32768000;
    const size_t OFF_LSE = 32784384;
    const size_t OFF_XQ  = 32800768;                 // 16 MB fp8 X
    const size_t OFF_WQ  = OFF_XQ + 16777216;        // 512 MB fp8 W (x64 scaled)

    float* pm  = (float*)ws;
    float* pl  = (float*)(ws + OFF_PL);
    float* tgt = (float*)(ws + OFF_TGT);
    float* lse = (float*)(ws + OFF_LSE);
    unsigned char* Xq = (unsigned char*)(ws + OFF_XQ);
    unsigned char* Wq = (unsigned char*)(ws + OFF_WQ);

    cvt_f32_fp8_kernel<<<4096, 256, 0, stream>>>(W, Wq, (size_t)V_DIM * H_DIM, 64.0f);
    cvt_f32_fp8_kernel<<<512, 256, 0, stream>>>(X, Xq, (size_t)N_ROWS * H_DIM, 1.0f);
    lmce_gemm256_kernel<<<NT_N * NT_V, 512, 0, stream>>>(Xq, Wq, pm, pl);
    lmce_tgt_kernel<<<N_ROWS, 256, 0, stream>>>(X, W, y, tgt);
    lmce_lse_kernel<<<N_ROWS / 64, 256, 0, stream>>>(pm, pl, lse);
    lmce_final_kernel<<<1, 256, 0, stream>>>(lse, tgt, y, out);
}

// Round 13
// 3391.534 us; speedup vs baseline: 8.8886x; 8.8886x over previous
//
#include <hip/hip_runtime.h>
#include <hip/hip_bf16.h>
#include <math.h>

// Fused LM-head cross-entropy: loss = mean_valid( logsumexp(x@W^T) - logit[y] )
// N=4096 tokens, H=4096 hidden, V=128000 vocab.
//
// Round 13: R10 base (MX-fp8 256^2 8-wave, identity scales, 2.92ms GEMM)
// with phases merged 4->2 per K-tile (8 mfma_scale per phase instead of 4):
// fp8's short MFMA clusters couldn't amortize the per-phase skeleton
// (~1750 cyc wall vs 550 productive). Keeps per-phase read/stage/MFMA
// interleave + counted vmcnt(4) ledger (re-derived, see comments).
// NOTE: __launch_bounds__ 2nd arg is min waves/SIMD; per-SIMD VGPR pool is
// 512 => (512,4) caps waves at 128 regs and spills (R12: 150GB scratch).
// Keep (512,2) = 256-reg cap, proven no-spill in R10.

#define N_ROWS 4096
#define H_DIM  4096
#define V_DIM  128000
#define BM 256
#define BN 256
#define NT_N (N_ROWS / BM)      // 16
#define NT_V (V_DIM / BN)       // 500
#define NKT  (H_DIM / 128)      // 32 K-tiles (128 fp8 elems each)
#define IGNORE_INDEX (-100)

typedef __attribute__((ext_vector_type(4))) int   i32x4;
typedef __attribute__((ext_vector_type(8))) int   i32x8;
typedef __attribute__((ext_vector_type(4))) float f32x4;
typedef __attribute__((ext_vector_type(16))) float f32x16;
typedef const __attribute__((address_space(1))) unsigned int* gas1_u32;
typedef __attribute__((address_space(3))) unsigned int* las3_u32;

// ---------------- exact f32 -> e4m3fn (OCP), RNE, saturating ----------------
__device__ __forceinline__ unsigned f2e4m3(float f) {
    unsigned u = __float_as_uint(f);
    unsigned s = (u >> 24) & 0x80u;
    float af = __uint_as_float(u & 0x7FFFFFFFu);
    unsigned code;
    if (af >= 0.015625f) {                       // normal range [2^-6, 448]
        if (af > 448.f) af = 448.f;
        unsigned v = __float_as_uint(af);
        v += 0x7FFFFu + ((v >> 20) & 1u);        // RNE to 3 mantissa bits
        unsigned m3 = (v >> 20) & 7u;
        int E = (int)(v >> 23) - 127;
        if (E > 8) { E = 8; m3 = 6u; }           // clamp to 448
        code = (unsigned)((E + 7) << 3) | m3;
    } else {                                      // subnormal: m * 2^-9
        code = (unsigned)rintf(af * 512.0f);     // 0..8 (8 -> 2^-6 seamlessly)
    }
    return s | code;
}

__global__ void cvt_f32_fp8_kernel(const float* __restrict__ in,
                                   unsigned char* __restrict__ out, size_t n, float scale)
{
    size_t i = ((size_t)blockIdx.x * blockDim.x + threadIdx.x) * 8;
    size_t stride = (size_t)gridDim.x * blockDim.x * 8;
    for (; i < n; i += stride) {
        f32x4 a = *(const f32x4*)(in + i);
        f32x4 b = *(const f32x4*)(in + i + 4);
        unsigned long long o;
        o  = (unsigned long long)f2e4m3(a.x * scale);
        o |= (unsigned long long)f2e4m3(a.y * scale) << 8;
        o |= (unsigned long long)f2e4m3(a.z * scale) << 16;
        o |= (unsigned long long)f2e4m3(a.w * scale) << 24;
        o |= (unsigned long long)f2e4m3(b.x * scale) << 32;
        o |= (unsigned long long)f2e4m3(b.y * scale) << 40;
        o |= (unsigned long long)f2e4m3(b.z * scale) << 48;
        o |= (unsigned long long)f2e4m3(b.w * scale) << 56;
        *(unsigned long long*)(out + i) = o;
    }
}

#define BAR()    asm volatile("s_barrier" ::: "memory")
#define WAITV4() asm volatile("s_waitcnt vmcnt(4)" ::: "memory")
#define SETP1()  __builtin_amdgcn_s_setprio(1)
#define SETP0()  __builtin_amdgcn_s_setprio(0)
#define SCL1 ((int)0x7F7F7F7F)   // E8M0 127 = 2^0 in every byte (identity)

// stage one half-tile (2 x 16B gload_lds per thread); dest linear, src pre-swizzled
#define STAGE_A(BUF, HALF, KT)                                                         \
    { _Pragma("unroll")                                                                \
      for (int j_ = 0; j_ < 2; ++j_)                                                   \
          __builtin_amdgcn_global_load_lds(                                            \
              (gas1_u32)(gAr + (size_t)((HALF)*128 + j_*64) * 4096 + (size_t)(KT)*128),\
              (las3_u32)((char*)lsA + (BUF)*32768 + (HALF)*16384 + j_*8192 + tid*16),  \
              16, 0, 0); }
#define STAGE_B(BUF, HALF, KT)                                                         \
    { _Pragma("unroll")                                                                \
      for (int j_ = 0; j_ < 2; ++j_)                                                   \
          __builtin_amdgcn_global_load_lds(                                            \
              (gas1_u32)(gBr + (size_t)((HALF)*128 + j_*64) * 4096 + (size_t)(KT)*128),\
              (las3_u32)((char*)lsB + (BUF)*32768 + (HALF)*16384 + j_*8192 + tid*16),  \
              16, 0, 0); }

// 32B fragment read: low 16B at off, high 16B at off^16 (k-base is 32-aligned
// so the XOR swizzle preserves k-ascending byte order across the pair).
__device__ __forceinline__ i32x8 rd32(const char* base, int off) {
    i32x8 r;
    *(i32x4*)&r       = *(const i32x4*)(base + off);
    *((i32x4*)&r + 1) = *(const i32x4*)(base + (off ^ 16));
    return r;
}

#define RD_ALO(BUF) { _Pragma("unroll") for (int m_=0;m_<2;++m_) { _Pragma("unroll")   \
    for (int k_=0;k_<2;++k_) aLo[m_][k_] = rd32(lsAc + (BUF)*32768, offA[m_][k_]); } }
#define RD_AHI(BUF) { _Pragma("unroll") for (int m_=0;m_<2;++m_) { _Pragma("unroll")   \
    for (int k_=0;k_<2;++k_) aHi[m_][k_] = rd32(lsAc + (BUF)*32768, offA[m_+2][k_]); } }
#define RD_BALL(BUF) { _Pragma("unroll") for (int n_=0;n_<2;++n_) { _Pragma("unroll")  \
    for (int k_=0;k_<2;++k_) bF[n_][k_] = rd32(lsBc + (BUF)*32768, offB[n_][k_]); } }

// 8 MFMAs: acc[MB..MB+1][0..1], ks outermost (consecutive insts independent)
#define MFMA_OCT(AF, MB)                                                               \
    { _Pragma("unroll")                                                                \
      for (int ks_=0; ks_<2; ++ks_) { _Pragma("unroll")                                \
        for (int m_=0; m_<2; ++m_) { _Pragma("unroll")                                 \
          for (int n_=0; n_<2; ++n_)                                                   \
            acc[(MB)+m_][n_] = __builtin_amdgcn_mfma_scale_f32_32x32x64_f8f6f4(        \
                AF[m_][ks_], bF[n_][ks_], acc[(MB)+m_][n_],                            \
                0, 0, 0, SCL1, 0, SCL1); } } }

// ------------------- 256^2 4-phase (2/K-tile) MX-fp8 GEMM -------------------
__global__ __launch_bounds__(512, 2)
void lmce_gemm256_kernel(const unsigned char* __restrict__ Xq, const unsigned char* __restrict__ Wq,
                         float* __restrict__ pm, float* __restrict__ pl)
{
    // [buf][half][128 rows][128 k-bytes] = 16KB per half; 64KB per operand
    __shared__ __align__(16) char lsA[2][2][128 * 128];
    __shared__ __align__(16) char lsB[2][2][128 * 128];
    __shared__ float red_m[4][BM];
    __shared__ float red_l[4][BM];
    const char* lsAc = (const char*)lsA;
    const char* lsBc = (const char*)lsB;

    // bijective XCD swizzle: nwg = 8000, divisible by 8
    const int nwg = NT_N * NT_V;
    int orig = blockIdx.x;
    int wg = (orig & 7) * (nwg >> 3) + (orig >> 3);
    int vtile = wg / NT_N;
    int ntile = wg - vtile * NT_N;

    int tid  = threadIdx.x;
    int lane = tid & 63;
    int w    = tid >> 6;         // 0..7
    int wr = w >> 2;             // 0..1 : which A half this wave consumes
    int wc = w & 3;              // 0..3 : which 64-col B strip
    int l31 = lane & 31;
    int kb  = (lane >> 5) * 32;  // k-byte base within a 64-elem step

    // staging source: thread covers row (tid>>3) of each 64-row chunk,
    // 16B at pre-swizzled col ((tid&7) ^ ((tid>>3)&7))*16
    int scolb = ((tid & 7) ^ ((tid >> 3) & 7)) * 16;
    const char* gAr = (const char*)Xq + (size_t)(ntile * BM + (tid >> 3)) * 4096 + scolb;
    const char* gBr = (const char*)Wq + (size_t)(vtile * BN + (tid >> 3)) * 4096 + scolb;

    // swizzled ds_read offsets (within one operand buffer; add buf*32768)
    int offA[4][2];
    #pragma unroll
    for (int mi = 0; mi < 4; ++mi)
        #pragma unroll
        for (int ks = 0; ks < 2; ++ks) {
            int row = mi * 32 + l31;
            offA[mi][ks] = wr * 16384 + row * 128 + ((kb + ks * 64) ^ ((row & 7) << 4));
        }
    int offB[2][2];
    #pragma unroll
    for (int ni = 0; ni < 2; ++ni)
        #pragma unroll
        for (int ks = 0; ks < 2; ++ks) {
            int row = (wc & 1) * 64 + ni * 32 + l31;
            offB[ni][ks] = (wc >> 1) * 16384 + row * 128 + ((kb + ks * 64) ^ ((row & 7) << 4));
        }

    f32x16 acc[4][2];
    #pragma unroll
    for (int i = 0; i < 4; ++i)
        #pragma unroll
        for (int j = 0; j < 2; ++j)
            #pragma unroll
            for (int r = 0; r < 16; ++r)
                acc[i][j][r] = 0.f;

    i32x8 aLo[2][2], aHi[2][2], bF[2][2];

    // prologue (mirrors steady state): B(0)x2, A(0)x2 [as prev-P1/P2],
    // then B(1)x2 [as prev-P3]. vmcnt(4): A(0),B(0) landed, B(1) in flight.
    STAGE_B(0, 0, 0); STAGE_B(0, 1, 0);
    STAGE_A(0, 0, 0); STAGE_A(0, 1, 0);
    STAGE_B(1, 0, 1); STAGE_B(1, 1, 1);
    WAITV4();
    BAR();

    for (int t = 0; t < NKT; t += 2) {
        int t2 = (t + 2 < NKT) ? t + 2 : NKT - 1;   // clamped dummy re-stage at tail
        int t3 = (t + 3 < NKT) ? t + 3 : NKT - 1;

        // ---- P0 (tile t, buf0): acc[0-1][0-1]
        // stage A(t+1): buf1 A last read prev-P3 (retired, barrier since).
        RD_ALO(0); RD_BALL(0);
        STAGE_A(1, 0, t + 1); STAGE_A(1, 1, t + 1);
        BAR();
        SETP1(); MFMA_OCT(aLo, 0); SETP0();
        BAR();

        // ---- P1: acc[2-3][0-1]
        // stage B(0)<-t+2: buf0 B reads retired before P0's MFMA, barrier since.
        RD_AHI(0);
        STAGE_B(0, 0, t2); STAGE_B(0, 1, t2);
        BAR();
        SETP1(); MFMA_OCT(aHi, 2); SETP0();
        // outstanding: B(t+1)4 [prev-P3], A(t+1)4 [P0], B(t+2)4 [P1]
        // vmcnt(4): A(t+1), B(t+1) landed for P2's reads.
        WAITV4();
        BAR();

        // ---- P2 (tile t+1, buf1): acc[0-1][0-1]
        // stage A(0)<-t+2: buf0 A reads (P0 aLo, P1 aHi) retired, barrier since.
        RD_ALO(1); RD_BALL(1);
        STAGE_A(0, 0, t2); STAGE_A(0, 1, t2);
        BAR();
        SETP1(); MFMA_OCT(aLo, 0); SETP0();
        BAR();

        // ---- P3: acc[2-3][0-1]
        // stage B(1)<-t+3: buf1 B reads retired before P2's MFMA, barrier since.
        RD_AHI(1);
        STAGE_B(1, 0, t3); STAGE_B(1, 1, t3);
        BAR();
        SETP1(); MFMA_OCT(aHi, 2); SETP0();
        // outstanding: B(t+2)4, A(t+2)4, B(t+3)4 -> vmcnt(4): tile t+2 ready.
        WAITV4();
        BAR();
    }

    __syncthreads();   // full drain (vmcnt 0 + lgkm 0) before epilogue

    // Epilogue: per-row max and sumexp over this block's 256 cols.
    // 32x32 C/D layout: col = lane&31, row = (r&3) + 8*(r>>2) + 4*(lane>>5).
    // Unscale logits by 2^-6 (W was stored x64) -- exact power of two.
    const float inv64 = 0.015625f;
    #pragma unroll
    for (int mi = 0; mi < 4; ++mi) {
        #pragma unroll
        for (int r = 0; r < 16; ++r) {
            float v0 = acc[mi][0][r] * inv64;
            float v1 = acc[mi][1][r] * inv64;
            float mx = fmaxf(v0, v1);
            #pragma unroll
            for (int s = 1; s < 32; s <<= 1)
                mx = fmaxf(mx, __shfl_xor(mx, s, 64));
            float se = __expf(v0 - mx) + __expf(v1 - mx);
            #pragma unroll
            for (int s = 1; s < 32; s <<= 1)
                se += __shfl_xor(se, s, 64);
            if (l31 == 0) {
                int rloc = wr * 128 + mi * 32 + (r & 3) + 8 * (r >> 2) + 4 * (lane >> 5);
                red_m[wc][rloc] = mx;
                red_l[wc][rloc] = se;
            }
        }
    }
    __syncthreads();
    if (tid < BM) {
        float mm = red_m[0][tid], ll = red_l[0][tid];
        #pragma unroll
        for (int p = 1; p < 4; ++p) {
            float m2 = red_m[p][tid], l2 = red_l[p][tid];
            float m3 = fmaxf(mm, m2);
            ll = ll * __expf(mm - m3) + l2 * __expf(m2 - m3);
            mm = m3;
        }
        size_t idx = (size_t)vtile * N_ROWS + (size_t)(ntile * BM + tid);
        pm[idx] = mm;
        pl[idx] = ll;
    }
}

// tgt[row] = dot(x[row], W[y[row]]) in fp32 (exact vs reference)
__global__ void lmce_tgt_kernel(const float* __restrict__ X, const float* __restrict__ W,
                                const int* __restrict__ y, float* __restrict__ tgt)
{
    int row = blockIdx.x;
    int tid = threadIdx.x;
    int yv = y[row];
    float s = 0.f;
    if (yv >= 0 && yv < V_DIM) {
        const float* xr = X + (size_t)row * H_DIM;
        const float* wrow = W + (size_t)yv * H_DIM;
        #pragma unroll
        for (int j = 0; j < 4; ++j) {
            int idx = (tid + j * 256) * 4;
            f32x4 a = *(const f32x4*)(xr + idx);
            f32x4 b = *(const f32x4*)(wrow + idx);
            s += a.x * b.x + a.y * b.y + a.z * b.z + a.w * b.w;
        }
    }
    #pragma unroll
    for (int sh = 1; sh < 64; sh <<= 1) s += __shfl_xor(s, sh, 64);
    __shared__ float sred[4];
    if ((tid & 63) == 0) sred[tid >> 6] = s;
    __syncthreads();
    if (tid == 0) tgt[row] = sred[0] + sred[1] + sred[2] + sred[3];
}

// merge NT_V per-vtile (m,l) partials per row -> lse[row]
__global__ void lmce_lse_kernel(const float* __restrict__ pm, const float* __restrict__ pl,
                                float* __restrict__ lse)
{
    int tid = threadIdx.x;
    int row = blockIdx.x * 64 + (tid & 63);
    int part = tid >> 6;               // 0..3, each scans NT_V/4 = 125 vtiles
    const int per = NT_V / 4;
    float m = -INFINITY, l = 0.f;
    for (int vt = part * per; vt < (part + 1) * per; ++vt) {
        size_t idx = (size_t)vt * N_ROWS + row;
        float m2 = pm[idx], l2 = pl[idx];
        float mm = fmaxf(m, m2);
        l = l * __expf(m - mm) + l2 * __expf(m2 - mm);
        m = mm;
    }
    __shared__ float sm[4][64], sl[4][64];
    sm[part][tid & 63] = m;
    sl[part][tid & 63] = l;
    __syncthreads();
    if (tid < 64) {
        float M = sm[0][tid], L = sl[0][tid];
        #pragma unroll
        for (int p = 1; p < 4; ++p) {
            float m2 = sm[p][tid], l2 = sl[p][tid];
            float mm = fmaxf(M, m2);
            L = L * __expf(M - mm) + l2 * __expf(m2 - mm);
            M = mm;
        }
        lse[blockIdx.x * 64 + tid] = M + logf(L);
    }
}

__global__ void lmce_final_kernel(const float* __restrict__ lse, const float* __restrict__ tgt,
                                  const int* __restrict__ y, float* __restrict__ out)
{
    int tid = threadIdx.x;
    float s = 0.f, c = 0.f;
    for (int i = tid; i < N_ROWS; i += 256) {
        if (y[i] != IGNORE_INDEX) {
            s += lse[i] - tgt[i];
            c += 1.f;
        }
    }
    #pragma unroll
    for (int sh = 1; sh < 64; sh <<= 1) {
        s += __shfl_xor(s, sh, 64);
        c += __shfl_xor(c, sh, 64);
    }
    __shared__ float ss[4], cc[4];
    if ((tid & 63) == 0) { ss[tid >> 6] = s; cc[tid >> 6] = c; }
    __syncthreads();
    if (tid == 0) {
        float S = ss[0] + ss[1] + ss[2] + ss[3];
        float C = cc[0] + cc[1] + cc[2] + cc[3];
        out[0] = S / fmaxf(C, 1.f);
    }
}

extern "C" void kernel_launch(void* const* d_in, const int* in_sizes, int n_in,
                              void* d_out, int out_size, void* d_ws, size_t ws_size,
                              hipStream_t stream)
{
    const float* X = (const float*)d_in[0];   // [4096, 4096] fp32
    const int*   y = (const int*)d_in[1];     // [4096] labels
    const float* W = (const float*)d_in[2];   // [128000, 4096] fp32
    float* out = (float*)d_out;

    char* ws = (char*)d_ws;
    const size_t OFF_PL  = 16384000;
    const size_t OFF_TGT = 32768000;
    const size_t OFF_LSE = 32784384;
    const size_t OFF_XQ  = 32800768;                 // 16 MB fp8 X
    const size_t OFF_WQ  = OFF_XQ + 16777216;        // 512 MB fp8 W (x64 scaled)

    float* pm  = (float*)ws;
    float* pl  = (float*)(ws + OFF_PL);
    float* tgt = (float*)(ws + OFF_TGT);
    float* lse = (float*)(ws + OFF_LSE);
    unsigned char* Xq = (unsigned char*)(ws + OFF_XQ);
    unsigned char* Wq = (unsigned char*)(ws + OFF_WQ);

    cvt_f32_fp8_kernel<<<4096, 256, 0, stream>>>(W, Wq, (size_t)V_DIM * H_DIM, 64.0f);
    cvt_f32_fp8_kernel<<<512, 256, 0, stream>>>(X, Xq, (size_t)N_ROWS * H_DIM, 1.0f);
    lmce_gemm256_kernel<<<NT_N * NT_V, 512, 0, stream>>>(Xq, Wq, pm, pl);
    lmce_tgt_kernel<<<N_ROWS, 256, 0, stream>>>(X, W, y, tgt);
    lmce_lse_kernel<<<N_ROWS / 64, 256, 0, stream>>>(pm, pl, lse);
    lmce_final_kernel<<<1, 256, 0, stream>>>(lse, tgt, y, out);
}

// Round 14
// 2930.253 us; speedup vs baseline: 10.2879x; 1.1574x over previous
//
#include <hip/hip_runtime.h>
#include <hip/hip_bf16.h>
#include <math.h>

// Fused LM-head cross-entropy: loss = mean_valid( logsumexp(x@W^T) - logit[y] )
// N=4096 tokens, H=4096 hidden, V=128000 vocab.
//
// Round 14: MX-fp8 (identity scales) 256^2 tile with 16 WAVES (1024 thr),
// 64x64 per-wave output -> acc 64 VGPR, live ~116 <= 128 cap (4 waves/SIMD).
// Un-barriered {reads -> MFMA} region lets 4 waves/SIMD pipeline LDS reads
// under MFMA (m114). Double-buffered; stage t+2 after read-retire barrier;
// counted vmcnt(4); never drain to 0 in the loop.

#define N_ROWS 4096
#define H_DIM  4096
#define V_DIM  128000
#define BM 256
#define BN 256
#define NT_N (N_ROWS / BM)      // 16
#define NT_V (V_DIM / BN)       // 500
#define NKT  (H_DIM / 128)      // 32 K-tiles (128 fp8 elems each)
#define IGNORE_INDEX (-100)

typedef __attribute__((ext_vector_type(4))) int   i32x4;
typedef __attribute__((ext_vector_type(8))) int   i32x8;
typedef __attribute__((ext_vector_type(4))) float f32x4;
typedef __attribute__((ext_vector_type(16))) float f32x16;
typedef const __attribute__((address_space(1))) unsigned int* gas1_u32;
typedef __attribute__((address_space(3))) unsigned int* las3_u32;

// ---------------- exact f32 -> e4m3fn (OCP), RNE, saturating ----------------
__device__ __forceinline__ unsigned f2e4m3(float f) {
    unsigned u = __float_as_uint(f);
    unsigned s = (u >> 24) & 0x80u;
    float af = __uint_as_float(u & 0x7FFFFFFFu);
    unsigned code;
    if (af >= 0.015625f) {                       // normal range [2^-6, 448]
        if (af > 448.f) af = 448.f;
        unsigned v = __float_as_uint(af);
        v += 0x7FFFFu + ((v >> 20) & 1u);        // RNE to 3 mantissa bits
        unsigned m3 = (v >> 20) & 7u;
        int E = (int)(v >> 23) - 127;
        if (E > 8) { E = 8; m3 = 6u; }           // clamp to 448
        code = (unsigned)((E + 7) << 3) | m3;
    } else {                                      // subnormal: m * 2^-9
        code = (unsigned)rintf(af * 512.0f);     // 0..8 (8 -> 2^-6 seamlessly)
    }
    return s | code;
}

__global__ void cvt_f32_fp8_kernel(const float* __restrict__ in,
                                   unsigned char* __restrict__ out, size_t n, float scale)
{
    size_t i = ((size_t)blockIdx.x * blockDim.x + threadIdx.x) * 8;
    size_t stride = (size_t)gridDim.x * blockDim.x * 8;
    for (; i < n; i += stride) {
        f32x4 a = *(const f32x4*)(in + i);
        f32x4 b = *(const f32x4*)(in + i + 4);
        unsigned long long o;
        o  = (unsigned long long)f2e4m3(a.x * scale);
        o |= (unsigned long long)f2e4m3(a.y * scale) << 8;
        o |= (unsigned long long)f2e4m3(a.z * scale) << 16;
        o |= (unsigned long long)f2e4m3(a.w * scale) << 24;
        o |= (unsigned long long)f2e4m3(b.x * scale) << 32;
        o |= (unsigned long long)f2e4m3(b.y * scale) << 40;
        o |= (unsigned long long)f2e4m3(b.z * scale) << 48;
        o |= (unsigned long long)f2e4m3(b.w * scale) << 56;
        *(unsigned long long*)(out + i) = o;
    }
}

#define BAR()    asm volatile("s_barrier" ::: "memory")
#define WAITV4() asm volatile("s_waitcnt vmcnt(4)" ::: "memory")
#define SCL1 ((int)0x7F7F7F7F)   // E8M0 127 = 2^0 in every byte (identity)

// 32B fragment read: low 16B at off, high 16B at off^16 (k-base is 32-aligned
// so the XOR swizzle preserves k-ascending byte order across the pair).
__device__ __forceinline__ i32x8 rd32(const char* base, int off) {
    i32x8 r;
    *(i32x4*)&r       = *(const i32x4*)(base + off);
    *((i32x4*)&r + 1) = *(const i32x4*)(base + (off ^ 16));
    return r;
}

// ------------------- 256^2 16-wave MX-fp8 GEMM -------------------
__global__ __launch_bounds__(1024)
void lmce_gemm256_kernel(const unsigned char* __restrict__ Xq, const unsigned char* __restrict__ Wq,
                         float* __restrict__ pm, float* __restrict__ pl)
{
    // [buf][256 rows][128 k-bytes] = 32KB per operand per buffer
    __shared__ __align__(16) char lsA[2][256 * 128];
    __shared__ __align__(16) char lsB[2][256 * 128];
    __shared__ float red_m[4][BM];
    __shared__ float red_l[4][BM];
    const char* lsAc = (const char*)lsA;
    const char* lsBc = (const char*)lsB;

    // bijective XCD swizzle: nwg = 8000, divisible by 8
    const int nwg = NT_N * NT_V;
    int orig = blockIdx.x;
    int wg = (orig & 7) * (nwg >> 3) + (orig >> 3);
    int vtile = wg / NT_N;
    int ntile = wg - vtile * NT_N;

    int tid  = threadIdx.x;
    int lane = tid & 63;
    int w    = tid >> 6;          // 0..15
    int wr = w >> 2;              // 0..3 : 64-row A strip
    int wc = w & 3;               // 0..3 : 64-col B strip
    int l31 = lane & 31;
    int kb  = (lane >> 5) * 32;   // k-byte base within a 64-elem half

    // staging: instr j covers LDS bytes [j*16384 + w*1024 + lane*16).
    // row = j*128 + w*8 + (lane>>3); row&7 = (lane>>3)&7 (indep of j,w).
    int scolb = (((lane & 7) ^ ((lane >> 3) & 7)) * 16);
    const char* gAr = (const char*)Xq + (size_t)(ntile * BM + w * 8 + (lane >> 3)) * 4096 + scolb;
    const char* gBr = (const char*)Wq + (size_t)(vtile * BN + w * 8 + (lane >> 3)) * 4096 + scolb;

    // swizzled ds_read offsets (within one buffer; add buf*32768)
    int offA[2][2], offB[2][2];
    #pragma unroll
    for (int mi = 0; mi < 2; ++mi)
        #pragma unroll
        for (int ks = 0; ks < 2; ++ks) {
            int rowA = wr * 64 + mi * 32 + l31;
            offA[mi][ks] = rowA * 128 + ((kb + ks * 64) ^ ((rowA & 7) << 4));
            int rowB = wc * 64 + mi * 32 + l31;
            offB[mi][ks] = rowB * 128 + ((kb + ks * 64) ^ ((rowB & 7) << 4));
        }

    f32x16 acc[2][2];
    #pragma unroll
    for (int i = 0; i < 2; ++i)
        #pragma unroll
        for (int j = 0; j < 2; ++j)
            #pragma unroll
            for (int r = 0; r < 16; ++r)
                acc[i][j][r] = 0.f;

    // stage one full tile (A 2 + B 2 instructions) into BUF from K-tile KT
    #define STAGE_TILE(BUF, KT)                                                        \
        { _Pragma("unroll")                                                            \
          for (int j_ = 0; j_ < 2; ++j_) {                                             \
              __builtin_amdgcn_global_load_lds(                                        \
                  (gas1_u32)(gAr + (size_t)j_ * 524288 + (size_t)(KT) * 128),          \
                  (las3_u32)((char*)lsA + (BUF) * 32768 + j_ * 16384 + w * 1024),      \
                  16, 0, 0);                                                           \
              __builtin_amdgcn_global_load_lds(                                        \
                  (gas1_u32)(gBr + (size_t)j_ * 524288 + (size_t)(KT) * 128),          \
                  (las3_u32)((char*)lsB + (BUF) * 32768 + j_ * 16384 + w * 1024),      \
                  16, 0, 0); } }

    // prologue: tile0 -> buf0 (4 loads), tile1 -> buf1 (4 loads)
    STAGE_TILE(0, 0);
    STAGE_TILE(1, 1);
    WAITV4();   // tile0's 4 landed (tile1's 4 in flight)
    BAR();

    for (int t = 0; t < NKT; ++t) {
        int buf = t & 1;
        int t2 = (t + 2 < NKT) ? t + 2 : NKT - 1;   // clamped dummy at tail
        const char* Ab = lsAc + buf * 32768;
        const char* Bb = lsBc + buf * 32768;

        // ks = 0: 4 fragment reads + 4 independent MFMAs (waves free-run here;
        // 4 waves/SIMD pipeline reads under other waves' MFMAs)
        {
            i32x8 a0 = rd32(Ab, offA[0][0]);
            i32x8 a1 = rd32(Ab, offA[1][0]);
            i32x8 b0 = rd32(Bb, offB[0][0]);
            i32x8 b1 = rd32(Bb, offB[1][0]);
            acc[0][0] = __builtin_amdgcn_mfma_scale_f32_32x32x64_f8f6f4(a0, b0, acc[0][0], 0, 0, 0, SCL1, 0, SCL1);
            acc[0][1] = __builtin_amdgcn_mfma_scale_f32_32x32x64_f8f6f4(a0, b1, acc[0][1], 0, 0, 0, SCL1, 0, SCL1);
            acc[1][0] = __builtin_amdgcn_mfma_scale_f32_32x32x64_f8f6f4(a1, b0, acc[1][0], 0, 0, 0, SCL1, 0, SCL1);
            acc[1][1] = __builtin_amdgcn_mfma_scale_f32_32x32x64_f8f6f4(a1, b1, acc[1][1], 0, 0, 0, SCL1, 0, SCL1);
        }
        // ks = 1
        {
            i32x8 a0 = rd32(Ab, offA[0][1]);
            i32x8 a1 = rd32(Ab, offA[1][1]);
            i32x8 b0 = rd32(Bb, offB[0][1]);
            i32x8 b1 = rd32(Bb, offB[1][1]);
            acc[0][0] = __builtin_amdgcn_mfma_scale_f32_32x32x64_f8f6f4(a0, b0, acc[0][0], 0, 0, 0, SCL1, 0, SCL1);
            acc[0][1] = __builtin_amdgcn_mfma_scale_f32_32x32x64_f8f6f4(a0, b1, acc[0][1], 0, 0, 0, SCL1, 0, SCL1);
            acc[1][0] = __builtin_amdgcn_mfma_scale_f32_32x32x64_f8f6f4(a1, b0, acc[1][0], 0, 0, 0, SCL1, 0, SCL1);
            acc[1][1] = __builtin_amdgcn_mfma_scale_f32_32x32x64_f8f6f4(a1, b1, acc[1][1], 0, 0, 0, SCL1, 0, SCL1);
        }

        BAR();   // every wave's reads of buf retired (consumed by its MFMAs)

        STAGE_TILE(buf, t2);   // overwrite own (fully-read) buffer with t+2

        // outstanding: tile t+1 (4, oldest) + tile t+2 (4 just issued).
        WAITV4();              // tile t+1 landed
        BAR();                 // publish t+1 to all waves
    }

    __syncthreads();   // full drain before epilogue

    // Epilogue: per-row max and sumexp over this block's 256 cols.
    // 32x32 C/D layout: col = lane&31, row = (r&3) + 8*(r>>2) + 4*(lane>>5).
    // Unscale logits by 2^-6 (W was stored x64) -- exact power of two.
    const float inv64 = 0.015625f;
    #pragma unroll
    for (int mi = 0; mi < 2; ++mi) {
        #pragma unroll
        for (int r = 0; r < 16; ++r) {
            float v0 = acc[mi][0][r] * inv64;
            float v1 = acc[mi][1][r] * inv64;
            float mx = fmaxf(v0, v1);
            #pragma unroll
            for (int s = 1; s < 32; s <<= 1)
                mx = fmaxf(mx, __shfl_xor(mx, s, 64));
            float se = __expf(v0 - mx) + __expf(v1 - mx);
            #pragma unroll
            for (int s = 1; s < 32; s <<= 1)
                se += __shfl_xor(se, s, 64);
            if (l31 == 0) {
                int rloc = wr * 64 + mi * 32 + (r & 3) + 8 * (r >> 2) + 4 * (lane >> 5);
                red_m[wc][rloc] = mx;
                red_l[wc][rloc] = se;
            }
        }
    }
    __syncthreads();
    if (tid < BM) {
        float mm = red_m[0][tid], ll = red_l[0][tid];
        #pragma unroll
        for (int p = 1; p < 4; ++p) {
            float m2 = red_m[p][tid], l2 = red_l[p][tid];
            float m3 = fmaxf(mm, m2);
            ll = ll * __expf(mm - m3) + l2 * __expf(m2 - m3);
            mm = m3;
        }
        size_t idx = (size_t)vtile * N_ROWS + (size_t)(ntile * BM + tid);
        pm[idx] = mm;
        pl[idx] = ll;
    }
    #undef STAGE_TILE
}

// tgt[row] = dot(x[row], W[y[row]]) in fp32 (exact vs reference)
__global__ void lmce_tgt_kernel(const float* __restrict__ X, const float* __restrict__ W,
                                const int* __restrict__ y, float* __restrict__ tgt)
{
    int row = blockIdx.x;
    int tid = threadIdx.x;
    int yv = y[row];
    float s = 0.f;
    if (yv >= 0 && yv < V_DIM) {
        const float* xr = X + (size_t)row * H_DIM;
        const float* wrow = W + (size_t)yv * H_DIM;
        #pragma unroll
        for (int j = 0; j < 4; ++j) {
            int idx = (tid + j * 256) * 4;
            f32x4 a = *(const f32x4*)(xr + idx);
            f32x4 b = *(const f32x4*)(wrow + idx);
            s += a.x * b.x + a.y * b.y + a.z * b.z + a.w * b.w;
        }
    }
    #pragma unroll
    for (int sh = 1; sh < 64; sh <<= 1) s += __shfl_xor(s, sh, 64);
    __shared__ float sred[4];
    if ((tid & 63) == 0) sred[tid >> 6] = s;
    __syncthreads();
    if (tid == 0) tgt[row] = sred[0] + sred[1] + sred[2] + sred[3];
}

// merge NT_V per-vtile (m,l) partials per row -> lse[row]
__global__ void lmce_lse_kernel(const float* __restrict__ pm, const float* __restrict__ pl,
                                float* __restrict__ lse)
{
    int tid = threadIdx.x;
    int row = blockIdx.x * 64 + (tid & 63);
    int part = tid >> 6;               // 0..3, each scans NT_V/4 = 125 vtiles
    const int per = NT_V / 4;
    float m = -INFINITY, l = 0.f;
    for (int vt = part * per; vt < (part + 1) * per; ++vt) {
        size_t idx = (size_t)vt * N_ROWS + row;
        float m2 = pm[idx], l2 = pl[idx];
        float mm = fmaxf(m, m2);
        l = l * __expf(m - mm) + l2 * __expf(m2 - mm);
        m = mm;
    }
    __shared__ float sm[4][64], sl[4][64];
    sm[part][tid & 63] = m;
    sl[part][tid & 63] = l;
    __syncthreads();
    if (tid < 64) {
        float M = sm[0][tid], L = sl[0][tid];
        #pragma unroll
        for (int p = 1; p < 4; ++p) {
            float m2 = sm[p][tid], l2 = sl[p][tid];
            float mm = fmaxf(M, m2);
            L = L * __expf(M - mm) + l2 * __expf(m2 - mm);
            M = mm;
        }
        lse[blockIdx.x * 64 + tid] = M + logf(L);
    }
}

__global__ void lmce_final_kernel(const float* __restrict__ lse, const float* __restrict__ tgt,
                                  const int* __restrict__ y, float* __restrict__ out)
{
    int tid = threadIdx.x;
    float s = 0.f, c = 0.f;
    for (int i = tid; i < N_ROWS; i += 256) {
        if (y[i] != IGNORE_INDEX) {
            s += lse[i] - tgt[i];
            c += 1.f;
        }
    }
    #pragma unroll
    for (int sh = 1; sh < 64; sh <<= 1) {
        s += __shfl_xor(s, sh, 64);
        c += __shfl_xor(c, sh, 64);
    }
    __shared__ float ss[4], cc[4];
    if ((tid & 63) == 0) { ss[tid >> 6] = s; cc[tid >> 6] = c; }
    __syncthreads();
    if (tid == 0) {
        float S = ss[0] + ss[1] + ss[2] + ss[3];
        float C = cc[0] + cc[1] + cc[2] + cc[3];
        out[0] = S / fmaxf(C, 1.f);
    }
}

extern "C" void kernel_launch(void* const* d_in, const int* in_sizes, int n_in,
                              void* d_out, int out_size, void* d_ws, size_t ws_size,
                              hipStream_t stream)
{
    const float* X = (const float*)d_in[0];   // [4096, 4096] fp32
    const int*   y = (const int*)d_in[1];     // [4096] labels
    const float* W = (const float*)d_in[2];   // [128000, 4096] fp32
    float* out = (float*)d_out;

    char* ws = (char*)d_ws;
    const size_t OFF_PL  = 16384000;
    const size_t OFF_TGT = 32768000;
    const size_t OFF_LSE = 32784384;
    const size_t OFF_XQ  = 32800768;                 // 16 MB fp8 X
    const size_t OFF_WQ  = OFF_XQ + 16777216;        // 512 MB fp8 W (x64 scaled)

    float* pm  = (float*)ws;
    float* pl  = (float*)(ws + OFF_PL);
    float* tgt = (float*)(ws + OFF_TGT);
    float* lse = (float*)(ws + OFF_LSE);
    unsigned char* Xq = (unsigned char*)(ws + OFF_XQ);
    unsigned char* Wq = (unsigned char*)(ws + OFF_WQ);

    cvt_f32_fp8_kernel<<<4096, 256, 0, stream>>>(W, Wq, (size_t)V_DIM * H_DIM, 64.0f);
    cvt_f32_fp8_kernel<<<512, 256, 0, stream>>>(X, Xq, (size_t)N_ROWS * H_DIM, 1.0f);
    lmce_gemm256_kernel<<<NT_N * NT_V, 1024, 0, stream>>>(Xq, Wq, pm, pl);
    lmce_tgt_kernel<<<N_ROWS, 256, 0, stream>>>(X, W, y, tgt);
    lmce_lse_kernel<<<N_ROWS / 64, 256, 0, stream>>>(pm, pl, lse);
    lmce_final_kernel<<<1, 256, 0, stream>>>(lse, tgt, y, out);
}